// Round 8
// baseline (1184.018 us; speedup 1.0000x reference)
//
#include <hip/hip_runtime.h>

// GraphSAGE 3-layer: N=100000, E=3.2M, 128 -> 128 -> 128 -> 64.
// Round 8: src-ordered sliding-window gather with register-owned accumulation.
//  - buckets of 64 dst nodes (2048 coarse bins = dst>>6)
//  - fine_sort: per bucket, counting-sort edges by key (d&7)<<9|(src>>8):
//    groups by owner wave, src-ascending within. Writes sorted edges, wptr
//    (per-wave segment starts), cnt (node degrees).
//  - gather_fused<C>: block=512=8 waves/bucket, wave w owns nodes d&7==w,
//    acc in VGPRs (8 nodes x C/64 cols/lane), edges via coalesced 64-batch +
//    readlane broadcast (uniform scalar branches, no atomics, no LDS).
//    All blocks walk src ascending -> coherent L2/L3 window.
//  - layers/GEMMs unchanged from round 6 (mfma, transform-before-agg L3).

#define NN 100000
#define CHUNK 8192
#define NBK ((NN + 63) / 64)   // 1563 buckets
#define FCAP 3072              // bucket edge capacity (mean 2048, sigma~45)

typedef _Float16 half_t;
typedef __attribute__((ext_vector_type(2))) _Float16 half2v;
typedef __attribute__((ext_vector_type(4))) _Float16 half4v;
typedef __attribute__((ext_vector_type(8))) _Float16 half8v;
typedef __attribute__((ext_vector_type(4))) float float4v;

// ---- Pass A: coarse histogram, 2048 bins (dst>>6) ----
__global__ __launch_bounds__(256) void coarse_hist_kernel(const int* __restrict__ dst,
                                                          int* __restrict__ ghist, int E) {
    __shared__ int h[2048];
    int tid = threadIdx.x;
    for (int i = tid; i < 2048; i += 256) h[i] = 0;
    __syncthreads();
    int base = blockIdx.x * CHUNK;
    int nE = min(CHUNK, E - base);
    for (int i = tid; i < nE; i += 256) atomicAdd(&h[dst[base + i] >> 6], 1);
    __syncthreads();
    for (int i = tid; i < 2048; i += 256) {
        int v = h[i];
        if (v) atomicAdd(&ghist[i], v);
    }
}

// ---- Pass B: scan 2048 coarse bins -> cptr/cfill ----
__global__ __launch_bounds__(1024) void coarse_scan_kernel(const int* __restrict__ ghist,
                                                           int* __restrict__ cptr,
                                                           int* __restrict__ cfill) {
    __shared__ int s[1024];
    int tid = threadIdx.x;
    int v0 = ghist[2 * tid], v1 = ghist[2 * tid + 1];
    s[tid] = v0 + v1;
    __syncthreads();
    for (int off = 1; off < 1024; off <<= 1) {
        int v = (tid >= off) ? s[tid - off] : 0;
        __syncthreads();
        s[tid] += v;
        __syncthreads();
    }
    int base = (tid == 0) ? 0 : s[tid - 1];
    cptr[2 * tid] = base;
    cfill[2 * tid] = base;
    cptr[2 * tid + 1] = base + v0;
    cfill[2 * tid + 1] = base + v0;
    if (tid == 1023) cptr[2048] = base + v0 + v1;  // == E
}

// ---- Pass C: partition edges into 2048 coarse buckets (packed u32) ----
__global__ __launch_bounds__(256) void partition_kernel(const int* __restrict__ src,
                                                        const int* __restrict__ dst,
                                                        int* __restrict__ cfill,
                                                        unsigned int* __restrict__ coarse,
                                                        int E) {
    __shared__ int h[2048];
    __shared__ int off[2048];
    __shared__ int gbase[2048];
    __shared__ int ssum[256];
    __shared__ unsigned int stage[CHUNK];
    int tid = threadIdx.x;
    for (int i = tid; i < 2048; i += 256) h[i] = 0;
    __syncthreads();
    int base = blockIdx.x * CHUNK;
    int nE = min(CHUNK, E - base);
    for (int i = tid; i < nE; i += 256) atomicAdd(&h[dst[base + i] >> 6], 1);
    __syncthreads();
    int b0 = tid * 8;
    int sum = 0;
#pragma unroll
    for (int j = 0; j < 8; j++) sum += h[b0 + j];
    ssum[tid] = sum;
    __syncthreads();
    for (int o = 1; o < 256; o <<= 1) {
        int v = (tid >= o) ? ssum[tid - o] : 0;
        __syncthreads();
        ssum[tid] += v;
        __syncthreads();
    }
    int run = (tid == 0) ? 0 : ssum[tid - 1];
#pragma unroll
    for (int j = 0; j < 8; j++) { off[b0 + j] = run; run += h[b0 + j]; }
    __syncthreads();
    for (int i = tid; i < nE; i += 256) {
        int d = dst[base + i];
        int s_ = src[base + i];
        int bin = d >> 6;
        int pos = atomicAdd(&off[bin], 1);
        stage[pos] = ((unsigned)(d & 63) << 17) | (unsigned)s_;
    }
    __syncthreads();
#pragma unroll
    for (int j = 0; j < 8; j++) {
        int b = b0 + j;
        if (h[b]) gbase[b] = atomicAdd(&cfill[b], h[b]);
    }
#pragma unroll
    for (int j = 0; j < 8; j++) {
        int b = b0 + j;
        int c = h[b];
        int lstart = off[b] - c;
        int gs = gbase[b];
        for (int k = 0; k < c; k++) coarse[gs + k] = stage[lstart + k];
    }
}

// ---- Pass D: fine sort per bucket by (owner=d&7, src>>8); emits sorted edges,
//      wptr (per-wave starts), cnt (node degrees) ----
__global__ __launch_bounds__(512) void fine_sort_kernel(
    const unsigned int* __restrict__ coarse, const int* __restrict__ cptr,
    unsigned int* __restrict__ sorted, int* __restrict__ wptr,
    int* __restrict__ cnt, int n) {
    __shared__ unsigned int stage[FCAP];
    __shared__ int hist[4096];
    __shared__ int part[512];
    __shared__ int cnt64[64];
    int b = blockIdx.x;
    int beg = cptr[b], end = cptr[b + 1];
    int nb = min(end - beg, FCAP);
    int tid = threadIdx.x;
    for (int i = tid; i < nb; i += 512) stage[i] = coarse[beg + i];
    for (int i = tid; i < 4096; i += 512) hist[i] = 0;
    if (tid < 64) cnt64[tid] = 0;
    __syncthreads();
    for (int i = tid; i < nb; i += 512) {
        unsigned p = stage[i];
        int d = p >> 17;
        int key = ((d & 7) << 9) | ((p & 0x1FFFFu) >> 8);
        atomicAdd(&hist[key], 1);
        atomicAdd(&cnt64[d], 1);
    }
    __syncthreads();
    // scan 4096 bins: thread owns 8
    int t8 = tid * 8;
    int loc[8];
    int s = 0;
#pragma unroll
    for (int j = 0; j < 8; j++) { loc[j] = hist[t8 + j]; s += loc[j]; }
    part[tid] = s;
    __syncthreads();
    for (int o = 1; o < 512; o <<= 1) {
        int v = (tid >= o) ? part[tid - o] : 0;
        __syncthreads();
        part[tid] += v;
        __syncthreads();
    }
    int run = (tid == 0) ? 0 : part[tid - 1];
#pragma unroll
    for (int j = 0; j < 8; j++) { hist[t8 + j] = run; run += loc[j]; }
    __syncthreads();
    if (tid < 8) wptr[b * 8 + tid] = beg + hist[tid * 512];  // capture before scatter
    if (tid < 64) {
        int node = b * 64 + tid;
        if (node < n) cnt[node] = cnt64[tid];
    }
    __syncthreads();
    for (int i = tid; i < nb; i += 512) {
        unsigned p = stage[i];
        int d = p >> 17;
        int key = ((d & 7) << 9) | ((p & 0x1FFFFu) >> 8);
        int pos = atomicAdd(&hist[key], 1);
        sorted[beg + pos] = p;
    }
}

// ---- fused gather: bucket/block, wave w owns nodes d&7==w, register acc.
//      Edges src-ascending -> sliding-window locality. No LDS, no atomics. ----
template <int C>  // 128 (2 cols/lane) or 64 (1 col/lane)
__global__ __launch_bounds__(512) void gather_fused(
    const half_t* __restrict__ h, const unsigned int* __restrict__ sorted,
    const int* __restrict__ wptr, const int* __restrict__ cptr,
    const int* __restrict__ cnt, half_t* __restrict__ mean, int n) {
    constexpr int CPL = C / 64;  // cols per lane
    int b = blockIdx.x;
    int w = threadIdx.x >> 6;
    int lane = threadIdx.x & 63;
    int s0 = wptr[b * 8 + w];
    int s1 = (w < 7) ? wptr[b * 8 + w + 1] : cptr[b + 1];
    float acc[8][CPL];
#pragma unroll
    for (int r = 0; r < 8; r++)
#pragma unroll
        for (int c = 0; c < CPL; c++) acc[r][c] = 0.f;

    const half_t* basep = h + lane * CPL;
    for (int j = s0; j < s1; j += 64) {
        int m = min(64, s1 - j);
        unsigned pv = (j + lane < s1) ? sorted[j + lane] : 0u;
        for (int k0 = 0; k0 < m; k0 += 8) {
            int kc = min(8, m - k0);
            unsigned pk[8];
            float fv[8][CPL];
#pragma unroll
            for (int u = 0; u < 8; u++) {
                if (u < kc) {
                    pk[u] = (unsigned)__builtin_amdgcn_readlane((int)pv, k0 + u);
                    int sidx = (int)(pk[u] & 0x1FFFFu);
                    if (CPL == 2) {
                        half2v v = *(const half2v*)(basep + (size_t)sidx * C);
                        fv[u][0] = (float)v.x;
                        fv[u][1] = (float)v.y;
                    } else {
                        fv[u][0] = (float)basep[(size_t)sidx * C];
                    }
                }
            }
#pragma unroll
            for (int u = 0; u < 8; u++) {
                if (u < kc) {
                    int r = (int)((pk[u] >> 20) & 7u);  // d>>3
#pragma unroll
                    for (int rr = 0; rr < 8; rr++) {
                        if (r == rr) {
#pragma unroll
                            for (int c = 0; c < CPL; c++) acc[rr][c] += fv[u][c];
                        }
                    }
                }
            }
        }
    }
#pragma unroll
    for (int r = 0; r < 8; r++) {
        int node = b * 64 + r * 8 + w;
        if (node < n) {
            int cN = cnt[node];
            float inv = (cN > 0) ? 1.0f / (float)cN : 0.0f;
            if (CPL == 2) {
                half2v out = {(half_t)(acc[r][0] * inv), (half_t)(acc[r][1] * inv)};
                *(half2v*)(mean + (size_t)node * C + lane * 2) = out;
            } else {
                mean[(size_t)node * C + lane] = (half_t)(acc[r][0] * inv);
            }
        }
    }
}

// ---- fp32 -> fp16 cast (row-major) ----
__global__ void cast_f2h(const float* __restrict__ in, half_t* __restrict__ out, int n4) {
    int t = blockIdx.x * blockDim.x + threadIdx.x;
    if (t < n4) {
        float4 v = *(const float4*)(in + (size_t)t * 4);
        half4v r = {(half_t)v.x, (half_t)v.y, (half_t)v.z, (half_t)v.w};
        *(half4v*)(out + (size_t)t * 4) = r;
    }
}

// ---- weight prep: fragment-contiguous fp16; all 6 weights in one launch ----
template <int C_IN, int C_OUT>
__device__ inline void prep_one(const float* __restrict__ W, half_t* __restrict__ B, int t) {
    constexpr int NCT = C_OUT / 16;
    if (t >= C_IN * C_OUT) return;
    int jj = t & 7;
    int kq = (t >> 3) & 3;
    int c = (t >> 5) & 15;
    int ct = (t >> 9) % NCT;
    int chunk = t / (512 * NCT);
    int k = chunk * 32 + kq * 8 + jj;
    int j = ct * 16 + c;
    B[t] = (half_t)W[(size_t)j * C_IN + k];
}

__global__ __launch_bounds__(256) void prep_all(
    const float* __restrict__ Wl1, const float* __restrict__ Wr1,
    const float* __restrict__ Wl2, const float* __restrict__ Wr2,
    const float* __restrict__ Wl3, const float* __restrict__ Wr3,
    half_t* Bl1, half_t* Br1, half_t* Bl2, half_t* Br2, half_t* Bl3, half_t* Br3) {
    int b = blockIdx.x;
    int tid = threadIdx.x;
    if (b < 256) {
        int sel = b >> 6;
        int t = (b & 63) * 256 + tid;
        const float* W = sel == 0 ? Wl1 : sel == 1 ? Wr1 : sel == 2 ? Wl2 : Wr2;
        half_t* B = sel == 0 ? Bl1 : sel == 1 ? Br1 : sel == 2 ? Bl2 : Br2;
        prep_one<128, 128>(W, B, t);
    } else {
        int idx = b - 256;
        int sel = idx >> 5;
        int t = (idx & 31) * 256 + tid;
        prep_one<128, 64>(sel == 0 ? Wl3 : Wr3, sel == 0 ? Bl3 : Br3, t);
    }
}

// ---- MFMA two-stage layer (layers 1,2) ----
template <int C_OUT>
__global__ __launch_bounds__(256) void mfma_layer(
    const half_t* __restrict__ rootA, const half_t* __restrict__ meanA,
    const half_t* __restrict__ Bl, const half_t* __restrict__ Br,
    const float* __restrict__ bias, half_t* __restrict__ out16, int n) {
    constexpr int NCT = C_OUT / 16;
    int tid = threadIdx.x;
    int w = tid >> 6;
    int l = tid & 63;
    int c = l & 15;
    int q = l >> 4;
    int row = blockIdx.x * 64 + w * 16 + c;
    int rowc = min(row, n - 1);

    float4v acc[NCT];
#pragma unroll
    for (int i = 0; i < NCT; i++) acc[i] = (float4v){0.f, 0.f, 0.f, 0.f};

#pragma unroll
    for (int s = 0; s < 2; s++) {
        const half_t* A = (s == 0 ? meanA : rootA) + (size_t)rowc * 128 + q * 8;
        const half_t* B = (s == 0 ? Bl : Br) + (size_t)(c * 4 + q) * 8;
#pragma unroll
        for (int ch = 0; ch < 4; ch++) {
            half8v a = *(const half8v*)(A + ch * 32);
            half8v b[NCT];
#pragma unroll
            for (int t2 = 0; t2 < NCT; t2++)
                b[t2] = *(const half8v*)(B + (size_t)ch * (NCT * 512) + t2 * 512);
#pragma unroll
            for (int t2 = 0; t2 < NCT; t2++)
                acc[t2] = __builtin_amdgcn_mfma_f32_16x16x32_f16(a, b[t2], acc[t2], 0, 0, 0);
        }
    }

    int orow0 = blockIdx.x * 64 + w * 16 + q * 4;
#pragma unroll
    for (int t2 = 0; t2 < NCT; t2++) {
        int col = t2 * 16 + c;
        float bv = bias[col];
#pragma unroll
        for (int r = 0; r < 4; r++) {
            int nrow = orow0 + r;
            if (nrow < n)
                out16[(size_t)nrow * C_OUT + col] = (half_t)fmaxf(acc[t2][r] + bv, 0.f);
        }
    }
}

// ---- MFMA single-stage (layer 3 pre/root) ----
template <int C_OUT, bool HAS_ADD, bool OUT32>
__global__ __launch_bounds__(256) void mfma_single(
    const half_t* __restrict__ A_, const half_t* __restrict__ Bp,
    const half_t* __restrict__ addv, const float* __restrict__ bias,
    float* __restrict__ out32, half_t* __restrict__ out16, int n) {
    constexpr int NCT = C_OUT / 16;
    int tid = threadIdx.x;
    int w = tid >> 6;
    int l = tid & 63;
    int c = l & 15;
    int q = l >> 4;
    int row = blockIdx.x * 64 + w * 16 + c;
    int rowc = min(row, n - 1);

    float4v acc[NCT];
#pragma unroll
    for (int i = 0; i < NCT; i++) acc[i] = (float4v){0.f, 0.f, 0.f, 0.f};

    const half_t* A = A_ + (size_t)rowc * 128 + q * 8;
    const half_t* B = Bp + (size_t)(c * 4 + q) * 8;
#pragma unroll
    for (int ch = 0; ch < 4; ch++) {
        half8v a = *(const half8v*)(A + ch * 32);
        half8v b[NCT];
#pragma unroll
        for (int t2 = 0; t2 < NCT; t2++)
            b[t2] = *(const half8v*)(B + (size_t)ch * (NCT * 512) + t2 * 512);
#pragma unroll
        for (int t2 = 0; t2 < NCT; t2++)
            acc[t2] = __builtin_amdgcn_mfma_f32_16x16x32_f16(a, b[t2], acc[t2], 0, 0, 0);
    }

    int orow0 = blockIdx.x * 64 + w * 16 + q * 4;
#pragma unroll
    for (int t2 = 0; t2 < NCT; t2++) {
        int col = t2 * 16 + c;
        float bv = bias ? bias[col] : 0.f;
#pragma unroll
        for (int r = 0; r < 4; r++) {
            int nrow = orow0 + r;
            if (nrow < n) {
                float v = acc[t2][r] + bv;
                if (HAS_ADD) v += (float)addv[(size_t)nrow * C_OUT + col];
                if (OUT32) out32[(size_t)nrow * C_OUT + col] = v;
                else       out16[(size_t)nrow * C_OUT + col] = (half_t)v;
            }
        }
    }
}

extern "C" void kernel_launch(void* const* d_in, const int* in_sizes, int n_in,
                              void* d_out, int out_size, void* d_ws, size_t ws_size,
                              hipStream_t stream) {
    const float* x   = (const float*)d_in[0];
    const int*   ei  = (const int*)d_in[1];
    const float* Wl1 = (const float*)d_in[2];
    const float* bl1 = (const float*)d_in[3];
    const float* Wr1 = (const float*)d_in[4];
    const float* Wl2 = (const float*)d_in[5];
    const float* bl2 = (const float*)d_in[6];
    const float* Wr2 = (const float*)d_in[7];
    const float* Wl3 = (const float*)d_in[8];
    const float* bl3 = (const float*)d_in[9];
    const float* Wr3 = (const float*)d_in[10];

    const int N = NN;
    const int E = in_sizes[1] / 2;
    const int* src = ei;
    const int* dst = ei + E;

    char* ws = (char*)d_ws;
    half_t* xh    = (half_t*)ws;                      // N*128
    half_t* hh    = xh + (size_t)N * 128;             // N*128
    half_t* meanh = hh + (size_t)N * 128;             // N*128 (z | meanz in layer 3)
    half_t* z     = meanh;                            // N*64
    half_t* meanz = meanh + (size_t)N * 64;           // N*64
    int* ghist    = (int*)(meanh + (size_t)N * 128);  // 2048
    int* cptr     = ghist + 2048;                     // 2049 (pad 2052)
    int* cfill    = cptr + 2052;                      // 2048
    int* cnt      = cfill + 2048;                     // N (pad +4)
    int* wptr     = cnt + N + 4;                      // NBK*8 (pad +8)
    unsigned int* coarse = (unsigned int*)(wptr + NBK * 8 + 8);  // E
    unsigned int* sorted = coarse + E;                // E
    half_t* Bl1 = (half_t*)(sorted + E);
    half_t* Br1 = Bl1 + 128 * 128;
    half_t* Bl2 = Br1 + 128 * 128;
    half_t* Br2 = Bl2 + 128 * 128;
    half_t* Bl3 = Br2 + 128 * 128;                    // 64*128
    half_t* Br3 = Bl3 + 64 * 128;

    // casts + weight prep
    cast_f2h<<<(N * 128 / 4 + 255) / 256, 256, 0, stream>>>(x, xh, N * 128 / 4);
    prep_all<<<320, 256, 0, stream>>>(Wl1, Wr1, Wl2, Wr2, Wl3, Wr3,
                                      Bl1, Br1, Bl2, Br2, Bl3, Br3);

    // sort build: hist -> scan -> partition -> fine sort (owner|src key)
    const int sort_blocks = (E + CHUNK - 1) / CHUNK;
    hipMemsetAsync(ghist, 0, 2048 * 4, stream);
    coarse_hist_kernel<<<sort_blocks, 256, 0, stream>>>(dst, ghist, E);
    coarse_scan_kernel<<<1, 1024, 0, stream>>>(ghist, cptr, cfill);
    partition_kernel<<<sort_blocks, 256, 0, stream>>>(src, dst, cfill, coarse, E);
    fine_sort_kernel<<<NBK, 512, 0, stream>>>(coarse, cptr, sorted, wptr, cnt, N);

    const int gemm_blocks = (N + 63) / 64;  // == NBK

    // Layer 1: xh -> hh (relu)
    gather_fused<128><<<NBK, 512, 0, stream>>>(xh, sorted, wptr, cptr, cnt, meanh, N);
    mfma_layer<128><<<gemm_blocks, 256, 0, stream>>>(xh, meanh, Bl1, Br1, bl1, hh, N);

    // Layer 2: hh -> hh (relu)
    gather_fused<128><<<NBK, 512, 0, stream>>>(hh, sorted, wptr, cptr, cnt, meanh, N);
    mfma_layer<128><<<gemm_blocks, 256, 0, stream>>>(hh, meanh, Bl2, Br2, bl2, hh, N);

    // Layer 3: z = hh@Wl3^T ; meanz = gather-mean(z) ; out = meanz + bl3 + hh@Wr3^T
    mfma_single<64, false, false><<<gemm_blocks, 256, 0, stream>>>(
        hh, Bl3, nullptr, nullptr, nullptr, z, N);
    gather_fused<64><<<NBK, 512, 0, stream>>>(z, sorted, wptr, cptr, cnt, meanz, N);
    mfma_single<64, true, true><<<gemm_blocks, 256, 0, stream>>>(
        hh, Br3, meanz, bl3, (float*)d_out, nullptr, N);
}